// Round 1
// baseline (140.041 us; speedup 1.0000x reference)
//
#include <hip/hip_runtime.h>
#include <hip/hip_bf16.h>
#include <cmath>

typedef __bf16 bf16_t;
typedef __attribute__((ext_vector_type(8)))  __bf16 bf16x8;
typedef __attribute__((ext_vector_type(16))) float  f32x16;
typedef __attribute__((ext_vector_type(4)))  float  f32x4;

#define HW    65536
#define BNC   8            // B * NUM_CHANS
#define CH    128          // gram chunks per bnc   (chunk = 512 px)
#define CBLK  128          // apply blocks per bnc  (block = 512 px)
#define FN    65536.0f
#define REPS  1e-12f

__device__ __forceinline__ bf16_t tob(float x){ return (bf16_t)x; }

// ---------------- Kernel A: partial channel-gram G (32x32) + channel sums ----------------
// One (b,nc) group = 32 channels of x. G = X * X^T over a 512-pixel chunk via MFMA:
// A and B are the SAME fragment (row=lane&31=channel, 8 consecutive pixels per lane),
// so the result is correct for any hardware k-permutation.
__global__ __launch_bounds__(256) void k_gram(const float* __restrict__ x,
                                              float* __restrict__ P,
                                              float* __restrict__ PS)
{
    const int bid   = blockIdx.x;
    const int bnc   = bid >> 7;          // / CH
    const int chunk = bid & (CH - 1);
    const int tid   = threadIdx.x;
    const int lane  = tid & 63;
    const int wv    = tid >> 6;
    const int ch    = lane & 31;
    const int hi    = lane >> 5;

    const float* px = x + ((size_t)(bnc * 32 + ch)) * HW
                        + chunk * (HW / CH) + wv * 128 + 8 * hi;

    f32x16 acc;
    #pragma unroll
    for (int r = 0; r < 16; ++r) acc[r] = 0.0f;
    float sx = 0.0f;

    #pragma unroll
    for (int s = 0; s < 8; ++s) {        // 8 k-steps of 16 pixels = 128 px per wave
        f32x4 u = *(const f32x4*)(px);
        f32x4 v = *(const f32x4*)(px + 4);
        px += 16;
        sx += (u.x + u.y + u.z + u.w) + (v.x + v.y + v.z + v.w);
        bf16x8 f;
        f[0]=tob(u.x); f[1]=tob(u.y); f[2]=tob(u.z); f[3]=tob(u.w);
        f[4]=tob(v.x); f[5]=tob(v.y); f[6]=tob(v.z); f[7]=tob(v.w);
        acc = __builtin_amdgcn_mfma_f32_32x32x16_bf16(f, f, acc, 0, 0, 0);
    }

    __shared__ float red[4][1024];
    __shared__ float sred[4][32];
    #pragma unroll
    for (int r = 0; r < 16; ++r) {
        int row = (r & 3) + 8 * (r >> 2) + 4 * hi;   // verified C/D layout
        red[wv][row * 32 + ch] = acc[r];
    }
    sx += __shfl_xor(sx, 32);
    if (hi == 0) sred[wv][ch] = sx;
    __syncthreads();

    float* Pp = P + (size_t)bid * 1024;
    #pragma unroll
    for (int i = 0; i < 4; ++i) {
        int e = tid + 256 * i;
        Pp[e] = red[0][e] + red[1][e] + red[2][e] + red[3][e];
    }
    if (tid < 32)
        PS[bid * 32 + tid] = sred[0][tid] + sred[1][tid] + sred[2][tid] + sred[3][tid];
}

// ---------------- Kernel B: reduce partials, do the attention algebra, emit M, K0 ----------
// out[b, nc*32+d, n] = K0[d] + sum_e2 M[d][e2] * x[b, nc*32+e2, n]
__global__ __launch_bounds__(1024) void k_attn(const float* __restrict__ P,
                                               const float* __restrict__ PS,
                                               const float* __restrict__ w_qkv,
                                               const float* __restrict__ b_qkv,
                                               const float* __restrict__ w_fus,
                                               const float* __restrict__ b_fus,
                                               const float* __restrict__ tin,
                                               float* __restrict__ M,
                                               float* __restrict__ K0)
{
    const int bnc = blockIdx.x;          // 8 blocks
    const int nc  = bnc & 3;
    const int tid = threadIdx.x;

    __shared__ float G[1024];
    __shared__ float Sx[32];

    {
        float g = 0.0f;
        const float* Pp = P + (size_t)bnc * CH * 1024;
        for (int c = 0; c < CH; ++c) g += Pp[c * 1024 + tid];
        G[tid] = g;
        if (tid < 32) {
            float s = 0.0f;
            const float* Sp = PS + bnc * CH * 32;
            for (int c = 0; c < CH; ++c) s += Sp[c * 32 + tid];
            Sx[tid] = s;
        }
    }
    __syncthreads();

    const int d = tid >> 5, j = tid & 31;
    const int cd = nc * 32 + d, cj = nc * 32 + j;
    const float Gdj = G[d * 32 + j], Gdd = G[d * 33], Gjj = G[j * 33];
    const float Sxd = Sx[d], Sxj = Sx[j];

    float mloc = 0.0f, kloc = 0.0f;
    #pragma unroll
    for (int e = 0; e < 2; ++e) {
        float aq = w_qkv[cd * 6 + e],     cq = b_qkv[cd * 6 + e];
        float ak = w_qkv[cj * 6 + 2 + e], ck = b_qkv[cj * 6 + 2 + e];
        float av = w_qkv[cj * 6 + 4 + e], cv = b_qkv[cj * 6 + 4 + e];
        float wf = w_fus[cd * 2 + e];
        float tv = tin[e * 4 + nc];

        float S  = aq * ak * Gdj + aq * ck * Sxd + cq * ak * Sxj + cq * ck * FN;
        float Nq = aq * aq * Gdd + 2.0f * aq * cq * Sxd + cq * cq * FN;
        float Nk = ak * ak * Gjj + 2.0f * ak * ck * Sxj + ck * ck * FN;
        float pre = S / (fmaxf(sqrtf(Nq), REPS) * fmaxf(sqrtf(Nk), REPS)) * tv;

        // softmax across j (aligned 32-lane groups inside a 64-wide wave)
        float mx = pre;
        #pragma unroll
        for (int o = 16; o; o >>= 1) mx = fmaxf(mx, __shfl_xor(mx, o));
        float p = expf(pre - mx);
        float sm = p;
        #pragma unroll
        for (int o = 16; o; o >>= 1) sm += __shfl_xor(sm, o);
        float A = p / sm;

        mloc += wf * A * av;
        kloc += wf * A * cv;
    }
    M[bnc * 1024 + d * 32 + j] = mloc;
    float kr = kloc;
    #pragma unroll
    for (int o = 16; o; o >>= 1) kr += __shfl_xor(kr, o);
    if (j == 0) K0[bnc * 32 + d] = b_fus[cd] + kr;
}

// ---------------- Kernel C: out = M (32x32) * x + K0, pixelwise via MFMA -------------------
__global__ __launch_bounds__(256) void k_apply(const float* __restrict__ x,
                                               const float* __restrict__ M,
                                               const float* __restrict__ K0,
                                               float* __restrict__ out)
{
    const int bid = blockIdx.x;
    const int bnc = bid >> 7;            // / CBLK
    const int blk = bid & (CBLK - 1);
    const int tid = threadIdx.x;
    const int lane = tid & 63;
    const int wv   = tid >> 6;
    const int rl   = lane & 31;          // A-row (=output channel d) and B/D col (=pixel)
    const int hi   = lane >> 5;

    // A fragments: M[d][k], k = 8*hi + j (+16 for second MFMA)
    const float* Mp = M + bnc * 1024 + rl * 32;
    bf16x8 ma0, ma1;
    {
        f32x4 a = *(const f32x4*)(Mp + 8 * hi);
        f32x4 b = *(const f32x4*)(Mp + 8 * hi + 4);
        f32x4 c = *(const f32x4*)(Mp + 16 + 8 * hi);
        f32x4 d4 = *(const f32x4*)(Mp + 16 + 8 * hi + 4);
        ma0[0]=tob(a.x); ma0[1]=tob(a.y); ma0[2]=tob(a.z); ma0[3]=tob(a.w);
        ma0[4]=tob(b.x); ma0[5]=tob(b.y); ma0[6]=tob(b.z); ma0[7]=tob(b.w);
        ma1[0]=tob(c.x); ma1[1]=tob(c.y); ma1[2]=tob(c.z); ma1[3]=tob(c.w);
        ma1[4]=tob(d4.x); ma1[5]=tob(d4.y); ma1[6]=tob(d4.z); ma1[7]=tob(d4.w);
    }
    float k0r[16];
    #pragma unroll
    for (int r = 0; r < 16; ++r)
        k0r[r] = K0[bnc * 32 + (r & 3) + 8 * (r >> 2) + 4 * hi];

    const size_t xbase = (size_t)bnc * 32 * HW;
    const int p0 = blk * (HW / CBLK) + wv * 128;

    for (int c = 0; c < 4; ++c) {        // 4 chunks of 32 pixels per wave
        const int pxi = p0 + c * 32 + rl;
        const float* xp = x + xbase + pxi;
        bf16x8 xb0, xb1;
        #pragma unroll
        for (int j = 0; j < 8; ++j) {
            float v0 = xp[(size_t)(8 * hi + j) * HW];
            float v1 = xp[(size_t)(16 + 8 * hi + j) * HW];
            xb0[j] = tob(v0);
            xb1[j] = tob(v1);
        }
        f32x16 acc;
        #pragma unroll
        for (int r = 0; r < 16; ++r) acc[r] = k0r[r];
        acc = __builtin_amdgcn_mfma_f32_32x32x16_bf16(ma0, xb0, acc, 0, 0, 0);
        acc = __builtin_amdgcn_mfma_f32_32x32x16_bf16(ma1, xb1, acc, 0, 0, 0);

        float* op = out + xbase + pxi;
        #pragma unroll
        for (int r = 0; r < 16; ++r) {
            int row = (r & 3) + 8 * (r >> 2) + 4 * hi;
            op[(size_t)row * HW] = acc[r];
        }
    }
}

// -------------------------------------------------------------------------------------------
extern "C" void kernel_launch(void* const* d_in, const int* in_sizes, int n_in,
                              void* d_out, int out_size, void* d_ws, size_t ws_size,
                              hipStream_t stream)
{
    (void)in_sizes; (void)n_in; (void)out_size;
    const float* x      = (const float*)d_in[0];
    const float* w_qkv  = (const float*)d_in[1];
    const float* b_qkv  = (const float*)d_in[2];
    const float* w_fus  = (const float*)d_in[3];
    const float* b_fus  = (const float*)d_in[4];
    const float* tin    = (const float*)d_in[5];
    float* out = (float*)d_out;

    // ws layout: [M (8*1024)][K0 (8*32)][P (8*CH*1024)][PS (8*CH*32)]
    float* Mbuf  = (float*)d_ws;
    float* K0buf = Mbuf + BNC * 1024;
    const size_t small = (size_t)(BNC * 1024 + BNC * 32);
    const size_t needP  = (size_t)BNC * CH * 1024;
    const size_t needPS = (size_t)BNC * CH * 32;
    float *P, *PS;
    if (ws_size >= (small + needP + needPS) * sizeof(float)) {
        P  = K0buf + BNC * 32;
        PS = P + needP;
    } else {
        // fall back: use d_out as scratch for the partials; kernel C fully
        // overwrites d_out afterwards, so this is safe (stream-ordered).
        P  = out;
        PS = out + needP;
    }

    k_gram <<<BNC * CH,  256,  0, stream>>>(x, P, PS);
    k_attn <<<BNC,       1024, 0, stream>>>(P, PS, w_qkv, b_qkv, w_fus, b_fus, tin,
                                            Mbuf, K0buf);
    k_apply<<<BNC * CBLK, 256, 0, stream>>>(x, Mbuf, K0buf, out);
}